// Round 8
// baseline (1579.236 us; speedup 1.0000x reference)
//
#include <hip/hip_runtime.h>

#define N_NODES 50000
#define R_REL   4
#define E_NNZ   800000
#define ED_EDGES 200000
#define H_DIM   128
#define L_DIM   64

#define RN_TOTAL (R_REL * N_NODES)    // 200000
#define ETOT     (R_REL * E_NNZ)      // 3,200,000

// ----- CSR-build scan constants (direct-scatter build) -----
#define SCB2  196                     // ceil(200000 / 1024)

// ---------------- workspace layout (bytes); budget <= 213,601,536 ----------
//   S_f (53.23-82.83M)  dead after gemm1_f      -> inside Yall
//   S_n (82.83-112.43M) dead after gemm1_n      -> Yall + free strip
//   xall(112.43-131.63M) dead after spmm1       -> Ys_p
//   S_p (131.63-181.23M) dead after gemm1_p     -> h_f, h_n (+6.77M free strip)
//   h_p (188.0-213.6M)   dead after gemm2_p     -> Ys_f, z
//   h_f dead after gemm2_f -> Ys_n
//   Yall dead after spmm2z -> uvz (38.4 MB fused [U|z|V] records)
#define WS_RP    0u
#define WS_HIST  800256u           // 800 KB cnt/cursor table
#define WS_BSUM  2026496u
#define WS_BIAS3 2028544u
#define WS_CV    2030592u          // cse, persistent
#define WS_YALL  27630720u         // 76.8 MB merged bf16 [node][r][view][64]
#define WS_UVZ   27630720u         // 38.4 MB fp32 [node][U(64)|z(64)|V(64)]
#define WS_SF    53230720u
#define WS_SN    82830720u
#define WS_XALL  112430720u
#define WS_YSP   112430720u
#define WS_SP    131630720u
#define WS_HF    131630720u
#define WS_YSN   131630720u
#define WS_HN    157230720u
#define WS_HPR   188001536u
#define WS_YSF   188001536u
#define WS_Z     200801536u        // ends 213,601,536 == budget

__device__ __forceinline__ ushort f2bf(float f) {
    unsigned u = __float_as_uint(f);
    unsigned r = (u + 0x7fffu + ((u >> 16) & 1u)) >> 16;   // RNE
    return (ushort)r;
}
__device__ __forceinline__ float bf2f(ushort u) {
    return __uint_as_float(((unsigned)u) << 16);
}

// ---------------- bf16 staging: one merged 384B-stride table ----------------
__global__ void cast_xall_kernel(const float* __restrict__ xp, const float* __restrict__ xf,
                                 const float* __restrict__ xn, ushort* __restrict__ xall) {
    int i = blockIdx.x * 256 + threadIdx.x;
    if (i >= N_NODES * 192) return;
    int node = i / 192, k = i - node * 192;
    float v = 0.f;
    if (k < 62) v = xp[node * 62 + k];
    else if (k >= 64 && k < 138) {
        int j = k - 64, d = j >> 1;
        v = (j & 1) ? xn[node * 37 + d] : xf[node * 37 + d];
    }
    xall[i] = f2bf(v);
}

// ---------------- direct CSR build (no sort needed: within-row order free) --
__global__ void zero_cnt_kernel(int* __restrict__ cnt) {
    int i = blockIdx.x * 256 + threadIdx.x;
    if (i < RN_TOTAL) cnt[i] = 0;
}

__global__ void row_hist_kernel(const int* __restrict__ rows, int* __restrict__ cnt) {
    int g = blockIdx.x * 256 + threadIdx.x;
    if (g < ETOT) {
        int r = g / E_NNZ;
        atomicAdd(&cnt[r * N_NODES + rows[g]], 1);
    }
}

__global__ void scan_part_kernel(const int* __restrict__ cnt, int* __restrict__ bsum) {
    __shared__ int red[256];
    int base = blockIdx.x * 1024, t = threadIdx.x;
    int s = 0;
    #pragma unroll
    for (int i = 0; i < 4; i++) {
        int idx = base + i * 256 + t;
        if (idx < RN_TOTAL) s += cnt[idx];
    }
    red[t] = s; __syncthreads();
    for (int d = 128; d > 0; d >>= 1) {
        if (t < d) red[t] += red[t + d];
        __syncthreads();
    }
    if (t == 0) bsum[blockIdx.x] = red[0];
}

__global__ void scan_bsum_kernel(int* __restrict__ bsum, int* __restrict__ rp) {
    __shared__ int sh[512];
    int t = threadIdx.x;
    int v = (t < SCB2) ? bsum[t] : 0;
    sh[t] = v; __syncthreads();
    for (int d = 1; d < 512; d <<= 1) {
        int u = (t >= d) ? sh[t - d] : 0;
        __syncthreads();
        sh[t] += u;
        __syncthreads();
    }
    if (t < SCB2) bsum[t] = sh[t] - v;
    if (t == 0) rp[RN_TOTAL] = ETOT;
}

// writes exclusive-scan result into BOTH rp (row starts, persistent) and
// cnt (running cursor for the scatter).
__global__ void scan_final_kernel(int* __restrict__ cnt, const int* __restrict__ bsum,
                                  int* __restrict__ rp) {
    __shared__ int sh[256];
    int base = blockIdx.x * 1024, t = threadIdx.x;
    int c[4]; int s = 0;
    #pragma unroll
    for (int i = 0; i < 4; i++) {
        int idx = base + t * 4 + i;
        c[i] = (idx < RN_TOTAL) ? cnt[idx] : 0;
        s += c[i];
    }
    sh[t] = s; __syncthreads();
    for (int d = 1; d < 256; d <<= 1) {
        int u = (t >= d) ? sh[t - d] : 0;
        __syncthreads();
        sh[t] += u;
        __syncthreads();
    }
    int off = bsum[blockIdx.x] + sh[t] - s;
    #pragma unroll
    for (int i = 0; i < 4; i++) {
        int idx = base + t * 4 + i;
        if (idx < RN_TOTAL) { rp[idx] = off; cnt[idx] = off; }
        off += c[i];
    }
}

__global__ void scatter_direct_kernel(const int* __restrict__ rows, const int* __restrict__ cols,
                                      const float* __restrict__ vals, int* __restrict__ cur,
                                      int2* __restrict__ cse) {
    int g = blockIdx.x * 256 + threadIdx.x;
    if (g < ETOT) {
        int r = g / E_NNZ;
        int p = atomicAdd(&cur[r * N_NODES + rows[g]], 1);
        cse[p] = make_int2(cols[g], __float_as_int(vals[g]));
    }
}

// ---- layer-1 spmm, all 3 views. Pair-split wave: lane half h owns edge e+h,
// ---- each lane owns 2 dims via dword loads. 32-bit offsets, x4-pair unroll.
__global__ void spmm1_all_kernel(const ushort* __restrict__ xall,
                                 const int* __restrict__ rp, const int2* __restrict__ cse,
                                 float* __restrict__ Sp, float* __restrict__ Sf,
                                 float* __restrict__ Sn) {
    int wave = threadIdx.x >> 6, lane = threadIdx.x & 63;
    int row = blockIdx.x * 4 + wave;
    if (row >= N_NODES) return;
    int h = lane >> 5, j = lane & 31;
    unsigned d0 = 2u * (unsigned)j;
    unsigned po = d0;                 // p dims d0,d0+1 (62 real + 2 pad)
    unsigned fo = 64u + 2u * d0;      // fn interleave: f(d0),n(d0),f(d0+1),n(d0+1)
    for (int r = 0; r < R_REL; r++) {
        int e0 = rp[r * N_NODES + row], e1 = rp[r * N_NODES + row + 1];
        float ap0 = 0.f, ap1 = 0.f, af0 = 0.f, af1 = 0.f, an0 = 0.f, an1 = 0.f;
        int e = e0;
        for (; e + 8 <= e1; e += 8) {
            int2 qA = cse[e + h],     qB = cse[e + 2 + h];
            int2 qC = cse[e + 4 + h], qD = cse[e + 6 + h];
            unsigned bA = (unsigned)qA.x * 192u, bB = (unsigned)qB.x * 192u;
            unsigned bC = (unsigned)qC.x * 192u, bD = (unsigned)qD.x * 192u;
            ushort2 pA = *(const ushort2*)(xall + bA + po);
            ushort2 pB = *(const ushort2*)(xall + bB + po);
            ushort2 pC = *(const ushort2*)(xall + bC + po);
            ushort2 pD = *(const ushort2*)(xall + bD + po);
            ushort4 uA = *(const ushort4*)(xall + bA + fo);
            ushort4 uB = *(const ushort4*)(xall + bB + fo);
            ushort4 uC = *(const ushort4*)(xall + bC + fo);
            ushort4 uD = *(const ushort4*)(xall + bD + fo);
            float vA = __int_as_float(qA.y), vB = __int_as_float(qB.y);
            float vC = __int_as_float(qC.y), vD = __int_as_float(qD.y);
            ap0 += vA * bf2f(pA.x) + vB * bf2f(pB.x) + vC * bf2f(pC.x) + vD * bf2f(pD.x);
            ap1 += vA * bf2f(pA.y) + vB * bf2f(pB.y) + vC * bf2f(pC.y) + vD * bf2f(pD.y);
            af0 += vA * bf2f(uA.x) + vB * bf2f(uB.x) + vC * bf2f(uC.x) + vD * bf2f(uD.x);
            an0 += vA * bf2f(uA.y) + vB * bf2f(uB.y) + vC * bf2f(uC.y) + vD * bf2f(uD.y);
            af1 += vA * bf2f(uA.z) + vB * bf2f(uB.z) + vC * bf2f(uC.z) + vD * bf2f(uD.z);
            an1 += vA * bf2f(uA.w) + vB * bf2f(uB.w) + vC * bf2f(uC.w) + vD * bf2f(uD.w);
        }
        for (; e < e1; e += 2) {          // masked pair tail (v=0 for inactive half)
            int idx = e + h;
            int2 q = cse[idx < e1 ? idx : e1 - 1];
            float v = (idx < e1) ? __int_as_float(q.y) : 0.f;
            unsigned b = (unsigned)q.x * 192u;
            ushort2 p = *(const ushort2*)(xall + b + po);
            ushort4 u = *(const ushort4*)(xall + b + fo);
            ap0 += v * bf2f(p.x); ap1 += v * bf2f(p.y);
            af0 += v * bf2f(u.x); an0 += v * bf2f(u.y);
            af1 += v * bf2f(u.z); an1 += v * bf2f(u.w);
        }
        ap0 += __shfl_xor(ap0, 32); ap1 += __shfl_xor(ap1, 32);
        af0 += __shfl_xor(af0, 32); af1 += __shfl_xor(af1, 32);
        an0 += __shfl_xor(an0, 32); an1 += __shfl_xor(an1, 32);
        if (h == 0) {
            int d = (int)d0;
            if (d < 62) *(float2*)(Sp + row * 248 + r * 62 + d) = make_float2(ap0, ap1);
            float* sfp = Sf + row * 148 + r * 37;
            float* snp = Sn + row * 148 + r * 37;
            if (d < 37) { sfp[d] = af0; snp[d] = an0; }
            if (d < 36) { sfp[d + 1] = af1; snp[d + 1] = an1; }
        }
    }
}

// ---------------- GEMM1 (A-tile k-major in LDS: 2x ds_read_b128 per k) ------
__launch_bounds__(256)
__global__ void gemm1_kernel(const float* __restrict__ x, const float* __restrict__ S,
                             const float* __restrict__ Ws, const float* __restrict__ bs,
                             const float* __restrict__ Wr, const float* __restrict__ br,
                             float* __restrict__ h, int din) {
    __shared__ float sAT[62 * 68];        // [k][row], row-pad 68
    __shared__ float sW[62 * 132];
    int t = threadIdx.x;
    int i0 = blockIdx.x * 64;
    int rg = t >> 5, cg = t & 31;
    float acc[8][4] = {};
    for (int s = 0; s < 5; s++) {
        const float* Aptr; int astride;
        if (s == 0) { Aptr = x; astride = din; }
        else        { Aptr = S + (s - 1) * din; astride = 4 * din; }
        const float* Wp = (s == 0) ? Ws : (Wr + (s - 1) * H_DIM * din);
        __syncthreads();
        for (int idx = t; idx < 64 * din; idx += 256) {
            int rr = idx / din, k = idx - rr * din;
            int grow = i0 + rr;
            sAT[k * 68 + rr] = (grow < N_NODES) ? Aptr[grow * astride + k] : 0.f;
        }
        for (int idx = t; idx < H_DIM * din; idx += 256) {
            int j = idx / din, k = idx - j * din;
            sW[k * 132 + j] = Wp[j * din + k];
        }
        __syncthreads();
        for (int k = 0; k < din; k++) {
            float4 a01 = *(const float4*)&sAT[k * 68 + rg * 8];
            float4 a45 = *(const float4*)&sAT[k * 68 + rg * 8 + 4];
            float a[8] = {a01.x, a01.y, a01.z, a01.w, a45.x, a45.y, a45.z, a45.w};
            float4 w = *(const float4*)&sW[k * 132 + cg * 4];
            #pragma unroll
            for (int rr = 0; rr < 8; rr++) {
                acc[rr][0] += a[rr] * w.x; acc[rr][1] += a[rr] * w.y;
                acc[rr][2] += a[rr] * w.z; acc[rr][3] += a[rr] * w.w;
            }
        }
    }
    int j0 = cg * 4;
    float btot[4];
    #pragma unroll
    for (int cc = 0; cc < 4; cc++) {
        float b = bs[j0 + cc];
        #pragma unroll
        for (int r = 0; r < R_REL; r++) b += br[r * H_DIM + j0 + cc];
        btot[cc] = b;
    }
    #pragma unroll
    for (int rr = 0; rr < 8; rr++) {
        int grow = i0 + rg * 8 + rr;
        if (grow < N_NODES) {
            float4 o;
            o.x = fmaxf((acc[rr][0] + btot[0]) * 0.2f, 0.f);
            o.y = fmaxf((acc[rr][1] + btot[1]) * 0.2f, 0.f);
            o.z = fmaxf((acc[rr][2] + btot[2]) * 0.2f, 0.f);
            o.w = fmaxf((acc[rr][3] + btot[3]) * 0.2f, 0.f);
            *(float4*)&h[grow * H_DIM + j0] = o;
        }
    }
}

// -------- GEMM2: Yself fp32 (ct=0), Yall bf16 view-interleaved (ct=1..4) ----
// -------- A-tile k-major in LDS: 2x ds_read_b128 per k.
__launch_bounds__(256)
__global__ void gemm2_kernel(const float* __restrict__ h, const float* __restrict__ Ws2,
                             const float* __restrict__ Wr2, float* __restrict__ Yself,
                             ushort* __restrict__ Yall, int view) {
    __shared__ float sAT[64 * 136];       // [k][row], row-pad 136
    __shared__ float sW[64 * 68];
    int t = threadIdx.x;
    int i0 = blockIdx.x * 128;
    int ct = blockIdx.y;
    int rg = t >> 4, cg = t & 15;
    const float* Wp = (ct == 0) ? Ws2 : (Wr2 + (ct - 1) * 64 * H_DIM);
    float acc[8][4] = {};
    for (int kc = 0; kc < 2; kc++) {
        __syncthreads();
        for (int idx = t; idx < 128 * 64; idx += 256) {
            int rr = idx >> 6, k = idx & 63;
            int grow = i0 + rr;
            sAT[k * 136 + rr] = (grow < N_NODES) ? h[grow * H_DIM + kc * 64 + k] : 0.f;
        }
        for (int idx = t; idx < 64 * 64; idx += 256) {
            int j = idx >> 6, k = idx & 63;
            sW[k * 68 + j] = Wp[j * H_DIM + kc * 64 + k];
        }
        __syncthreads();
        for (int k = 0; k < 64; k++) {
            float4 a01 = *(const float4*)&sAT[k * 136 + rg * 8];
            float4 a45 = *(const float4*)&sAT[k * 136 + rg * 8 + 4];
            float a[8] = {a01.x, a01.y, a01.z, a01.w, a45.x, a45.y, a45.z, a45.w};
            float4 w = *(const float4*)&sW[k * 68 + cg * 4];
            #pragma unroll
            for (int rr = 0; rr < 8; rr++) {
                acc[rr][0] += a[rr] * w.x; acc[rr][1] += a[rr] * w.y;
                acc[rr][2] += a[rr] * w.z; acc[rr][3] += a[rr] * w.w;
            }
        }
    }
    #pragma unroll
    for (int rr = 0; rr < 8; rr++) {
        int grow = i0 + rg * 8 + rr;
        if (grow < N_NODES) {
            if (ct == 0) {
                float4 o = make_float4(acc[rr][0], acc[rr][1], acc[rr][2], acc[rr][3]);
                *(float4*)&Yself[(size_t)grow * 64 + cg * 4] = o;
            } else {
                ushort4 o;
                o.x = f2bf(acc[rr][0]); o.y = f2bf(acc[rr][1]);
                o.z = f2bf(acc[rr][2]); o.w = f2bf(acc[rr][3]);
                // [node][r][view][64] -> node*768 + r*192 + view*64 + dim
                *(ushort4*)&Yall[(size_t)grow * 768 + (ct - 1) * 192 + view * 64 + cg * 4] = o;
            }
        }
    }
}

// ---- fold bs + sum_r br per view into one 192-float table ----
__global__ void bias_prep_kernel(const float* __restrict__ pbs, const float* __restrict__ pbr,
                                 const float* __restrict__ fbs, const float* __restrict__ fbr,
                                 const float* __restrict__ nbs, const float* __restrict__ nbr,
                                 float* __restrict__ bias3) {
    int t = threadIdx.x;
    if (t >= 192) return;
    int view = t >> 6, d = t & 63;
    const float* bs = (view == 0) ? pbs : (view == 1) ? fbs : nbs;
    const float* br = (view == 0) ? pbr : (view == 1) ? fbr : nbr;
    float b = bs[d];
    #pragma unroll
    for (int r = 0; r < R_REL; r++) b += br[r * 64 + d];
    bias3[t] = b;
}

// ---- spmm2 (all 3 views from ONE merged table) + bias + /5 + gated fusion.
__launch_bounds__(256)
__global__ void spmm2z_all_kernel(const float* __restrict__ Ysp,
                                  const float* __restrict__ Ysf,
                                  const float* __restrict__ Ysn,
                                  const ushort* __restrict__ Yall,
                                  const int* __restrict__ rp, const int2* __restrict__ cse,
                                  const float* __restrict__ bias3,
                                  const float* __restrict__ gW, const float* __restrict__ gb,
                                  float* __restrict__ z) {
    int wave = threadIdx.x >> 6, lane = threadIdx.x & 63;
    int row = blockIdx.x * 4 + wave;
    if (row >= N_NODES) return;
    int h = lane >> 5, j = lane & 31;
    unsigned d0 = 2u * (unsigned)j;
    float aP0 = 0.f, aP1 = 0.f, aF0 = 0.f, aF1 = 0.f, aN0 = 0.f, aN1 = 0.f;
    for (int r = 0; r < R_REL; r++) {
        int e0 = rp[r * N_NODES + row], e1 = rp[r * N_NODES + row + 1];
        unsigned ofs = (unsigned)(r * 192) + d0;
        int e = e0;
        for (; e + 8 <= e1; e += 8) {
            int2 qA = cse[e + h],     qB = cse[e + 2 + h];
            int2 qC = cse[e + 4 + h], qD = cse[e + 6 + h];
            unsigned oA = (unsigned)qA.x * 768u + ofs;
            unsigned oB = (unsigned)qB.x * 768u + ofs;
            unsigned oC = (unsigned)qC.x * 768u + ofs;
            unsigned oD = (unsigned)qD.x * 768u + ofs;
            ushort2 pA = *(const ushort2*)(Yall + oA);
            ushort2 fA = *(const ushort2*)(Yall + oA + 64);
            ushort2 nA = *(const ushort2*)(Yall + oA + 128);
            ushort2 pB = *(const ushort2*)(Yall + oB);
            ushort2 fB = *(const ushort2*)(Yall + oB + 64);
            ushort2 nB = *(const ushort2*)(Yall + oB + 128);
            ushort2 pC = *(const ushort2*)(Yall + oC);
            ushort2 fC = *(const ushort2*)(Yall + oC + 64);
            ushort2 nC = *(const ushort2*)(Yall + oC + 128);
            ushort2 pD = *(const ushort2*)(Yall + oD);
            ushort2 fD = *(const ushort2*)(Yall + oD + 64);
            ushort2 nD = *(const ushort2*)(Yall + oD + 128);
            float vA = __int_as_float(qA.y), vB = __int_as_float(qB.y);
            float vC = __int_as_float(qC.y), vD = __int_as_float(qD.y);
            aP0 += vA * bf2f(pA.x) + vB * bf2f(pB.x) + vC * bf2f(pC.x) + vD * bf2f(pD.x);
            aP1 += vA * bf2f(pA.y) + vB * bf2f(pB.y) + vC * bf2f(pC.y) + vD * bf2f(pD.y);
            aF0 += vA * bf2f(fA.x) + vB * bf2f(fB.x) + vC * bf2f(fC.x) + vD * bf2f(fD.x);
            aF1 += vA * bf2f(fA.y) + vB * bf2f(fB.y) + vC * bf2f(fC.y) + vD * bf2f(fD.y);
            aN0 += vA * bf2f(nA.x) + vB * bf2f(nB.x) + vC * bf2f(nC.x) + vD * bf2f(nD.x);
            aN1 += vA * bf2f(nA.y) + vB * bf2f(nB.y) + vC * bf2f(nC.y) + vD * bf2f(nD.y);
        }
        for (; e < e1; e += 2) {          // masked pair tail
            int idx = e + h;
            int2 q = cse[idx < e1 ? idx : e1 - 1];
            float v = (idx < e1) ? __int_as_float(q.y) : 0.f;
            unsigned o = (unsigned)q.x * 768u + ofs;
            ushort2 p = *(const ushort2*)(Yall + o);
            ushort2 f = *(const ushort2*)(Yall + o + 64);
            ushort2 n = *(const ushort2*)(Yall + o + 128);
            aP0 += v * bf2f(p.x); aP1 += v * bf2f(p.y);
            aF0 += v * bf2f(f.x); aF1 += v * bf2f(f.y);
            aN0 += v * bf2f(n.x); aN1 += v * bf2f(n.y);
        }
    }
    // merge the two edge-halves
    aP0 += __shfl_xor(aP0, 32); aP1 += __shfl_xor(aP1, 32);
    aF0 += __shfl_xor(aF0, 32); aF1 += __shfl_xor(aF1, 32);
    aN0 += __shfl_xor(aN0, 32); aN1 += __shfl_xor(aN1, 32);
    size_t rb = (size_t)row * 64 + d0;
    float2 ysp = *(const float2*)(Ysp + rb);
    float2 ysf = *(const float2*)(Ysf + rb);
    float2 ysn = *(const float2*)(Ysn + rb);
    aP0 = (aP0 + ysp.x + bias3[d0]) * 0.2f;
    aP1 = (aP1 + ysp.y + bias3[d0 + 1]) * 0.2f;
    aF0 = (aF0 + ysf.x + bias3[64 + d0]) * 0.2f;
    aF1 = (aF1 + ysf.y + bias3[64 + d0 + 1]) * 0.2f;
    aN0 = (aN0 + ysn.x + bias3[128 + d0]) * 0.2f;
    aN1 = (aN1 + ysn.y + bias3[128 + d0 + 1]) * 0.2f;
    float sp = aP0 * gW[d0] + aP1 * gW[d0 + 1];
    float sf = aF0 * gW[64 + d0] + aF1 * gW[64 + d0 + 1];
    float sn = aN0 * gW[128 + d0] + aN1 * gW[128 + d0 + 1];
    #pragma unroll
    for (int d = 16; d >= 1; d >>= 1) {
        sp += __shfl_xor(sp, d);
        sf += __shfl_xor(sf, d);
        sn += __shfl_xor(sn, d);
    }
    sp += gb[0]; sf += gb[1]; sn += gb[2];
    float m = fmaxf(sp, fmaxf(sf, sn));
    float ep = __expf(sp - m), ef = __expf(sf - m), en = __expf(sn - m);
    float inv = 1.f / (ep + ef + en);
    if (h == 0) {
        float2 zo;
        zo.x = (ep * aP0 + ef * aF0 + en * aN0) * inv;
        zo.y = (ep * aP1 + ef * aF1 + en * aN1) * inv;
        *(float2*)(z + rb) = zo;
    }
}

// ---- UV precompute into fused uvz record [node][U(64)|z(64)|V(64)].
// ---- U = z @ W1a^T + b1 (ct=0, also copies z into the middle); V = z @ W1b^T (ct=1).
__launch_bounds__(256)
__global__ void uvgemm_kernel(const float* __restrict__ z, const float* __restrict__ w1,
                              const float* __restrict__ b1, float* __restrict__ uvz) {
    __shared__ float sAT[64 * 136];
    __shared__ float sW[64 * 68];
    int t = threadIdx.x;
    int i0 = blockIdx.x * 128;
    int ct = blockIdx.y;                  // 0 = U (+z copy), 1 = V
    int rg = t >> 4, cg = t & 15;
    for (int idx = t; idx < 128 * 64; idx += 256) {
        int rr = idx >> 6, k = idx & 63;
        int grow = i0 + rr;
        sAT[k * 136 + rr] = (grow < N_NODES) ? z[(size_t)grow * 64 + k] : 0.f;
    }
    for (int idx = t; idx < 64 * 64; idx += 256) {
        int j = idx >> 6, k = idx & 63;
        sW[k * 68 + j] = w1[j * 256 + ct * 64 + k];
    }
    __syncthreads();
    float acc[8][4] = {};
    for (int k = 0; k < 64; k++) {
        float4 a01 = *(const float4*)&sAT[k * 136 + rg * 8];
        float4 a45 = *(const float4*)&sAT[k * 136 + rg * 8 + 4];
        float a[8] = {a01.x, a01.y, a01.z, a01.w, a45.x, a45.y, a45.z, a45.w};
        float4 w = *(const float4*)&sW[k * 68 + cg * 4];
        #pragma unroll
        for (int rr = 0; rr < 8; rr++) {
            acc[rr][0] += a[rr] * w.x; acc[rr][1] += a[rr] * w.y;
            acc[rr][2] += a[rr] * w.z; acc[rr][3] += a[rr] * w.w;
        }
    }
    int j0 = cg * 4;
    float4 bv = make_float4(0.f, 0.f, 0.f, 0.f);
    if (ct == 0) {                        // fold b1 into U
        bv.x = b1[j0]; bv.y = b1[j0 + 1]; bv.z = b1[j0 + 2]; bv.w = b1[j0 + 3];
    }
    unsigned voff = (ct == 0) ? 0u : 128u;
    #pragma unroll
    for (int rr = 0; rr < 8; rr++) {
        int grow = i0 + rg * 8 + rr;
        if (grow < N_NODES) {
            float4 o = make_float4(acc[rr][0] + bv.x, acc[rr][1] + bv.y,
                                   acc[rr][2] + bv.z, acc[rr][3] + bv.w);
            *(float4*)&uvz[(size_t)grow * 192 + voff + j0] = o;
        }
    }
    if (ct == 0) {                        // copy z (already staged in sAT) into middle
        for (int idx = t; idx < 128 * 64; idx += 256) {
            int rr = idx >> 6, k = idx & 63;
            int grow = i0 + rr;
            if (grow < N_NODES) uvz[(size_t)grow * 192 + 64 + k] = sAT[k * 136 + rr];
        }
    }
}

// -------- decoder v9: 1 edge/thread, no j-split, fused uvz records.
// -------- Per edge: TWO contiguous 512B gather spans ([U|zs] @ s*192,
// -------- [zd|V] @ d*192+64) instead of 4 streams. hid[64] in regs,
// -------- W1c|W1d (32 KB) in LDS, direct logit write (no partials).
__launch_bounds__(256)
__global__ void decoder9_kernel(const float* __restrict__ uvz, const int* __restrict__ esrc,
                                const int* __restrict__ edst, const float* __restrict__ w1,
                                const float* __restrict__ w2, const float* __restrict__ b2,
                                float* __restrict__ out) {
    __shared__ float sW1[8192];           // 32 KB: 64 j-rows of [wc(64)|wd(64)]
    int t = threadIdx.x;
    for (int i = t; i < 2048; i += 256) {
        int j = i >> 5, c = i & 31;       // 32 float4 per j-row
        ((float4*)sW1)[i] = *(const float4*)(w1 + j * 256 + 128 + c * 4);
    }
    __syncthreads();
    int e = blockIdx.x * 256 + t;
    if (e >= ED_EDGES) return;
    int s = esrc[e], d = edst[e];
    const float4* su = (const float4*)(uvz + (size_t)s * 192);        // [U | zs]
    const float4* dv = (const float4*)(uvz + (size_t)d * 192 + 64);   // [zd | V]
    float hid[64];
    #pragma unroll
    for (int j = 0; j < 64; j++) hid[j] = 0.f;
    #pragma unroll 1
    for (int kc = 0; kc < 16; kc++) {
        float4 a = su[16 + kc];           // zs
        float4 b = dv[kc];                // zd
        float4 p, q;
        p.x = a.x * b.x; q.x = fabsf(a.x - b.x);
        p.y = a.y * b.y; q.y = fabsf(a.y - b.y);
        p.z = a.z * b.z; q.z = fabsf(a.z - b.z);
        p.w = a.w * b.w; q.w = fabsf(a.w - b.w);
        const float* wb0 = sW1 + kc * 4;
        #pragma unroll
        for (int j = 0; j < 64; j++) {
            const float* wr = wb0 + j * 128;
            float4 wc = *(const float4*)(wr);          // W1c row (broadcast)
            float4 wd = *(const float4*)(wr + 64);     // W1d row
            hid[j] += p.x * wc.x + p.y * wc.y + p.z * wc.z + p.w * wc.w
                    + q.x * wd.x + q.y * wd.y + q.z * wd.z + q.w * wd.w;
        }
    }
    float lg = b2[0];
    #pragma unroll
    for (int jj = 0; jj < 16; jj++) {
        float4 u = su[jj];                // U[s][4j..]
        float4 v = dv[16 + jj];           // V[d][4j..]
        int gj = jj * 4;
        float w0 = w2[gj], w1v = w2[gj + 1], w2v = w2[gj + 2], w3v = w2[gj + 3];
        lg += fmaxf(hid[gj]     + u.x + v.x, 0.f) * w0
            + fmaxf(hid[gj + 1] + u.y + v.y, 0.f) * w1v
            + fmaxf(hid[gj + 2] + u.z + v.z, 0.f) * w2v
            + fmaxf(hid[gj + 3] + u.w + v.w, 0.f) * w3v;
    }
    out[e] = lg;
}

// ---------------- host ----------------
extern "C" void kernel_launch(void* const* d_in, const int* in_sizes, int n_in,
                              void* d_out, int out_size, void* d_ws, size_t ws_size,
                              hipStream_t stream) {
    const float* x_p = (const float*)d_in[0];
    const float* x_f = (const float*)d_in[1];
    const float* x_n = (const float*)d_in[2];
    const float* p1_Ws = (const float*)d_in[3];  const float* p1_bs = (const float*)d_in[4];
    const float* p1_Wr = (const float*)d_in[5];  const float* p1_br = (const float*)d_in[6];
    const float* p2_Ws = (const float*)d_in[7];  const float* p2_bs = (const float*)d_in[8];
    const float* p2_Wr = (const float*)d_in[9];  const float* p2_br = (const float*)d_in[10];
    const float* f1_Ws = (const float*)d_in[11]; const float* f1_bs = (const float*)d_in[12];
    const float* f1_Wr = (const float*)d_in[13]; const float* f1_br = (const float*)d_in[14];
    const float* f2_Ws = (const float*)d_in[15]; const float* f2_bs = (const float*)d_in[16];
    const float* f2_Wr = (const float*)d_in[17]; const float* f2_br = (const float*)d_in[18];
    const float* n1_Ws = (const float*)d_in[19]; const float* n1_bs = (const float*)d_in[20];
    const float* n1_Wr = (const float*)d_in[21]; const float* n1_br = (const float*)d_in[22];
    const float* n2_Ws = (const float*)d_in[23]; const float* n2_bs = (const float*)d_in[24];
    const float* n2_Wr = (const float*)d_in[25]; const float* n2_br = (const float*)d_in[26];
    const float* gate_W = (const float*)d_in[27]; const float* gate_b = (const float*)d_in[28];
    const float* dec_W1 = (const float*)d_in[29]; const float* dec_b1 = (const float*)d_in[30];
    const float* dec_W2 = (const float*)d_in[31]; const float* dec_b2 = (const float*)d_in[32];
    const int*   adj_rows = (const int*)d_in[33];
    const int*   adj_cols = (const int*)d_in[34];
    const float* adj_vals = (const float*)d_in[35];
    const int*   edge_src = (const int*)d_in[36];
    const int*   edge_dst = (const int*)d_in[37];

    char* ws = (char*)d_ws;
    int*    rp   = (int*)(ws + WS_RP);
    int*    cnt  = (int*)(ws + WS_HIST);
    int*    bsum = (int*)(ws + WS_BSUM);
    float*  bias3 = (float*)(ws + WS_BIAS3);
    int2*   cse  = (int2*)(ws + WS_CV);
    ushort* xall = (ushort*)(ws + WS_XALL);
    ushort* Yall = (ushort*)(ws + WS_YALL);
    float*  S_p = (float*)(ws + WS_SP);
    float*  S_f = (float*)(ws + WS_SF);
    float*  S_n = (float*)(ws + WS_SN);
    float*  h_p = (float*)(ws + WS_HPR);
    float*  h_f = (float*)(ws + WS_HF);
    float*  h_n = (float*)(ws + WS_HN);
    float*  Ys_p = (float*)(ws + WS_YSP);
    float*  Ys_f = (float*)(ws + WS_YSF);
    float*  Ys_n = (float*)(ws + WS_YSN);
    float*  z    = (float*)(ws + WS_Z);
    float*  uvz  = (float*)(ws + WS_UVZ);
    float*  out  = (float*)d_out;

    // bf16 staging of node features (merged, 384B-stride, zero-padded)
    cast_xall_kernel<<<(N_NODES * 192 + 255) / 256, 256, 0, stream>>>(x_p, x_f, x_n, xall);

    // direct CSR build: zero -> row hist -> scan -> scatter (no sort needed)
    zero_cnt_kernel<<<(RN_TOTAL + 255) / 256, 256, 0, stream>>>(cnt);
    row_hist_kernel<<<(ETOT + 255) / 256, 256, 0, stream>>>(adj_rows, cnt);
    scan_part_kernel<<<SCB2, 256, 0, stream>>>(cnt, bsum);
    scan_bsum_kernel<<<1, 512, 0, stream>>>(bsum, rp);
    scan_final_kernel<<<SCB2, 256, 0, stream>>>(cnt, bsum, rp);
    scatter_direct_kernel<<<(ETOT + 255) / 256, 256, 0, stream>>>(
        adj_rows, adj_cols, adj_vals, cnt, cse);

    // layer-1 spmm for all 3 views
    spmm1_all_kernel<<<N_NODES / 4, 256, 0, stream>>>(xall, rp, cse, S_p, S_f, S_n);

    // layer-1 GEMMs -> h_v (fp32)
    int g1 = (N_NODES + 63) / 64;
    gemm1_kernel<<<g1, 256, 0, stream>>>(x_p, S_p, p1_Ws, p1_bs, p1_Wr, p1_br, h_p, 62);
    gemm1_kernel<<<g1, 256, 0, stream>>>(x_f, S_f, f1_Ws, f1_bs, f1_Wr, f1_br, h_f, 37);
    gemm1_kernel<<<g1, 256, 0, stream>>>(x_n, S_n, n1_Ws, n1_bs, n1_Wr, n1_br, h_n, 37);

    // layer-2 GEMMs: Yself fp32 + merged view-interleaved Yall bf16
    dim3 g2((N_NODES + 127) / 128, 5);
    gemm2_kernel<<<g2, 256, 0, stream>>>(h_p, p2_Ws, p2_Wr, Ys_p, Yall, 0);
    gemm2_kernel<<<g2, 256, 0, stream>>>(h_f, f2_Ws, f2_Wr, Ys_f, Yall, 1);
    gemm2_kernel<<<g2, 256, 0, stream>>>(h_n, n2_Ws, n2_Wr, Ys_n, Yall, 2);

    // fold biases, then spmm2 (all views, one table) + gated fusion -> z
    bias_prep_kernel<<<1, 192, 0, stream>>>(p2_bs, p2_br, f2_bs, f2_br, n2_bs, n2_br, bias3);
    spmm2z_all_kernel<<<N_NODES / 4, 256, 0, stream>>>(
        Ys_p, Ys_f, Ys_n, Yall, rp, cse, bias3, gate_W, gate_b, z);

    // fused per-node record [U | z | V] (Yall is dead now)
    dim3 guv((N_NODES + 127) / 128, 2);
    uvgemm_kernel<<<guv, 256, 0, stream>>>(z, dec_W1, dec_b1, uvz);

    // edge decoder: 1 edge/thread, 2 gather spans, direct logits
    decoder9_kernel<<<(ED_EDGES + 255) / 256, 256, 0, stream>>>(
        uvz, edge_src, edge_dst, dec_W1, dec_W2, dec_b2, out);
}

// Round 9
// 1374.342 us; speedup vs baseline: 1.1491x; 1.1491x over previous
//
#include <hip/hip_runtime.h>

#define N_NODES 50000
#define R_REL   4
#define E_NNZ   800000
#define ED_EDGES 200000
#define H_DIM   128
#define L_DIM   64

#define RN_TOTAL (R_REL * N_NODES)    // 200000
#define ETOT     (R_REL * E_NNZ)      // 3,200,000

// ----- radix CSR-build constants -----
#define EPB   8192
#define NB    391
#define RBK   196
#define KBK   (R_REL * RBK)           // 784
#define HTOT  (KBK * NB)              // 306,544
#define SCB   300
#define MAXB  6144

// ---------------- workspace layout (bytes); budget <= 213,601,536 ----------
//   tmp (27.63-53.23M)  dead after bucket_sort  -> inside Yall
//   S_f (53.23-82.83M)  dead after gemm1_f      -> inside Yall
//   S_n (82.83-112.43M) dead after gemm1_n      -> Yall + free strip
//   xall(112.43-131.63M) dead after spmm1       -> Ys_p
//   S_p (131.63-181.23M) dead after gemm1_p     -> h_f, h_n (+6.77M free strip)
//   h_p (188.0-213.6M)   dead after gemm2_p     -> Ys_f, z
//   h_f dead after gemm2_f -> Ys_n
//   Yall dead after spmm2z -> uvz (38.4 MB fused [U|z|V] records)
#define WS_RP    0u
#define WS_HIST  800256u
#define WS_BSUM  2026496u
#define WS_BIAS3 2028544u
#define WS_CV    2030592u          // cse, persistent
#define WS_YALL  27630720u         // 76.8 MB merged bf16 [node][r][view][64]
#define WS_TMP   27630720u
#define WS_UVZ   27630720u         // 38.4 MB fp32 [node][U(64)|z(64)|V(64)]
#define WS_SF    53230720u
#define WS_SN    82830720u
#define WS_XALL  112430720u
#define WS_YSP   112430720u
#define WS_SP    131630720u
#define WS_HF    131630720u
#define WS_YSN   131630720u
#define WS_HN    157230720u
#define WS_HPR   188001536u
#define WS_YSF   188001536u
#define WS_Z     200801536u        // ends 213,601,536 == budget

__device__ __forceinline__ ushort f2bf(float f) {
    unsigned u = __float_as_uint(f);
    unsigned r = (u + 0x7fffu + ((u >> 16) & 1u)) >> 16;   // RNE
    return (ushort)r;
}
__device__ __forceinline__ float bf2f(ushort u) {
    return __uint_as_float(((unsigned)u) << 16);
}

// ---- bf16 staging, vectorized: 8 elems/thread, two aligned ushort4 stores --
__global__ void cast_xall_kernel(const float* __restrict__ xp, const float* __restrict__ xf,
                                 const float* __restrict__ xn, ushort* __restrict__ xall) {
    int i8 = blockIdx.x * 256 + threadIdx.x;      // one 8-ushort chunk
    if (i8 >= N_NODES * 24) return;
    int node = i8 / 24, c = i8 - node * 24;
    int k0 = c * 8;
    ushort tmp[8];
    #pragma unroll
    for (int u = 0; u < 8; u++) {
        int k = k0 + u;
        float v = 0.f;
        if (k < 62) v = xp[node * 62 + k];
        else if (k >= 64 && k < 138) {
            int j = k - 64, d = j >> 1;
            v = (j & 1) ? xn[node * 37 + d] : xf[node * 37 + d];
        }
        tmp[u] = f2bf(v);
    }
    ushort4 lo = make_ushort4(tmp[0], tmp[1], tmp[2], tmp[3]);
    ushort4 hi = make_ushort4(tmp[4], tmp[5], tmp[6], tmp[7]);
    *(ushort4*)(xall + (size_t)i8 * 8) = lo;
    *(ushort4*)(xall + (size_t)i8 * 8 + 4) = hi;
}

// ---------------- radix CSR build ----------------
__global__ void radix_hist_kernel(const int* __restrict__ rows, int* __restrict__ H) {
    __shared__ int hist[KBK];
    int blk = blockIdx.x, t = threadIdx.x;
    for (int i = t; i < KBK; i += 256) hist[i] = 0;
    __syncthreads();
    int base = blk * EPB;
    #pragma unroll 1
    for (int i = 0; i < EPB / 256; i++) {
        int g = base + i * 256 + t;
        if (g < ETOT) {
            int r = g / E_NNZ;
            atomicAdd(&hist[r * RBK + (rows[g] >> 8)], 1);
        }
    }
    __syncthreads();
    for (int i = t; i < KBK; i += 256) H[i * NB + blk] = hist[i];
}

__global__ void scan_part_kernel(const int* __restrict__ H, int* __restrict__ bsum) {
    __shared__ int red[256];
    int base = blockIdx.x * 1024, t = threadIdx.x;
    int s = 0;
    #pragma unroll
    for (int i = 0; i < 4; i++) {
        int idx = base + i * 256 + t;
        if (idx < HTOT) s += H[idx];
    }
    red[t] = s; __syncthreads();
    for (int d = 128; d > 0; d >>= 1) {
        if (t < d) red[t] += red[t + d];
        __syncthreads();
    }
    if (t == 0) bsum[blockIdx.x] = red[0];
}

__global__ void scan_bsum_kernel(int* __restrict__ bsum, int* __restrict__ rp) {
    __shared__ int sh[512];
    int t = threadIdx.x;
    int v = (t < SCB) ? bsum[t] : 0;
    sh[t] = v; __syncthreads();
    for (int d = 1; d < 512; d <<= 1) {
        int u = (t >= d) ? sh[t - d] : 0;
        __syncthreads();
        sh[t] += u;
        __syncthreads();
    }
    if (t < SCB) bsum[t] = sh[t] - v;
    if (t == 0) rp[RN_TOTAL] = ETOT;
}

__global__ void scan_final_kernel(int* __restrict__ H, const int* __restrict__ bsum) {
    __shared__ int sh[256];
    int base = blockIdx.x * 1024, t = threadIdx.x;
    int c[4]; int s = 0;
    #pragma unroll
    for (int i = 0; i < 4; i++) {
        int idx = base + t * 4 + i;
        c[i] = (idx < HTOT) ? H[idx] : 0;
        s += c[i];
    }
    sh[t] = s; __syncthreads();
    for (int d = 1; d < 256; d <<= 1) {
        int u = (t >= d) ? sh[t - d] : 0;
        __syncthreads();
        sh[t] += u;
        __syncthreads();
    }
    int off = bsum[blockIdx.x] + sh[t] - s;
    #pragma unroll
    for (int i = 0; i < 4; i++) {
        int idx = base + t * 4 + i;
        if (idx < HTOT) H[idx] = off;
        off += c[i];
    }
}

__global__ void radix_scatter_kernel(const int* __restrict__ rows, const int* __restrict__ cols,
                                     const float* __restrict__ vals, const int* __restrict__ H,
                                     int2* __restrict__ tmp) {
    __shared__ int cur[KBK];
    int blk = blockIdx.x, t = threadIdx.x;
    for (int i = t; i < KBK; i += 256) cur[i] = H[i * NB + blk];
    __syncthreads();
    int base = blk * EPB;
    #pragma unroll 1
    for (int i = 0; i < EPB / 256; i++) {
        int g = base + i * 256 + t;
        if (g < ETOT) {
            int r = g / E_NNZ;
            int row = rows[g];
            int b = r * RBK + (row >> 8);
            int p = atomicAdd(&cur[b], 1);
            tmp[p] = make_int2(cols[g] | ((row & 255) << 16), __float_as_int(vals[g]));
        }
    }
}

__launch_bounds__(256)
__global__ void bucket_sort_kernel(const int2* __restrict__ tmp, const int* __restrict__ H,
                                   int* __restrict__ rp, int2* __restrict__ cse) {
    __shared__ int hist[256];
    __shared__ int sc[256];
    __shared__ int cur[256];
    __shared__ int2 eb[MAXB];
    int b = blockIdx.x, t = threadIdx.x;
    int start = H[b * NB];
    int end = (b == KBK - 1) ? ETOT : H[(b + 1) * NB];
    int cnt = end - start;
    bool useLds = (cnt <= MAXB);
    hist[t] = 0;
    __syncthreads();
    for (int i = t; i < cnt; i += 256) {
        int2 e = tmp[start + i];
        if (useLds) eb[i] = e;
        atomicAdd(&hist[(e.x >> 16) & 255], 1);
    }
    __syncthreads();
    sc[t] = hist[t]; __syncthreads();
    for (int d = 1; d < 256; d <<= 1) {
        int v = (t >= d) ? sc[t - d] : 0;
        __syncthreads();
        sc[t] += v;
        __syncthreads();
    }
    int pref = sc[t] - hist[t];
    int r = b / RBK, rh = b - r * RBK;
    int grow = rh * 256 + t;
    if (grow < N_NODES) rp[r * N_NODES + grow] = start + pref;
    cur[t] = start + pref;
    __syncthreads();
    for (int i = t; i < cnt; i += 256) {
        int2 e = useLds ? eb[i] : tmp[start + i];
        int rl = (e.x >> 16) & 255;
        int p = atomicAdd(&cur[rl], 1);
        cse[p] = make_int2(e.x & 0xFFFF, e.y);
    }
}

// ---- layer-1 spmm, all 3 views. Pair-split wave: lane half h owns edge e+h,
// ---- each lane owns 2 dims via dword loads. 32-bit offsets, x4-pair unroll.
__global__ void spmm1_all_kernel(const ushort* __restrict__ xall,
                                 const int* __restrict__ rp, const int2* __restrict__ cse,
                                 float* __restrict__ Sp, float* __restrict__ Sf,
                                 float* __restrict__ Sn) {
    int wave = threadIdx.x >> 6, lane = threadIdx.x & 63;
    int row = blockIdx.x * 4 + wave;
    if (row >= N_NODES) return;
    int h = lane >> 5, j = lane & 31;
    unsigned d0 = 2u * (unsigned)j;
    unsigned po = d0;                 // p dims d0,d0+1 (62 real + 2 pad)
    unsigned fo = 64u + 2u * d0;      // fn interleave: f(d0),n(d0),f(d0+1),n(d0+1)
    for (int r = 0; r < R_REL; r++) {
        int e0 = rp[r * N_NODES + row], e1 = rp[r * N_NODES + row + 1];
        float ap0 = 0.f, ap1 = 0.f, af0 = 0.f, af1 = 0.f, an0 = 0.f, an1 = 0.f;
        int e = e0;
        for (; e + 8 <= e1; e += 8) {
            int2 qA = cse[e + h],     qB = cse[e + 2 + h];
            int2 qC = cse[e + 4 + h], qD = cse[e + 6 + h];
            unsigned bA = (unsigned)qA.x * 192u, bB = (unsigned)qB.x * 192u;
            unsigned bC = (unsigned)qC.x * 192u, bD = (unsigned)qD.x * 192u;
            ushort2 pA = *(const ushort2*)(xall + bA + po);
            ushort2 pB = *(const ushort2*)(xall + bB + po);
            ushort2 pC = *(const ushort2*)(xall + bC + po);
            ushort2 pD = *(const ushort2*)(xall + bD + po);
            ushort4 uA = *(const ushort4*)(xall + bA + fo);
            ushort4 uB = *(const ushort4*)(xall + bB + fo);
            ushort4 uC = *(const ushort4*)(xall + bC + fo);
            ushort4 uD = *(const ushort4*)(xall + bD + fo);
            float vA = __int_as_float(qA.y), vB = __int_as_float(qB.y);
            float vC = __int_as_float(qC.y), vD = __int_as_float(qD.y);
            ap0 += vA * bf2f(pA.x) + vB * bf2f(pB.x) + vC * bf2f(pC.x) + vD * bf2f(pD.x);
            ap1 += vA * bf2f(pA.y) + vB * bf2f(pB.y) + vC * bf2f(pC.y) + vD * bf2f(pD.y);
            af0 += vA * bf2f(uA.x) + vB * bf2f(uB.x) + vC * bf2f(uC.x) + vD * bf2f(uD.x);
            an0 += vA * bf2f(uA.y) + vB * bf2f(uB.y) + vC * bf2f(uC.y) + vD * bf2f(uD.y);
            af1 += vA * bf2f(uA.z) + vB * bf2f(uB.z) + vC * bf2f(uC.z) + vD * bf2f(uD.z);
            an1 += vA * bf2f(uA.w) + vB * bf2f(uB.w) + vC * bf2f(uC.w) + vD * bf2f(uD.w);
        }
        for (; e < e1; e += 2) {          // masked pair tail (v=0 for inactive half)
            int idx = e + h;
            int2 q = cse[idx < e1 ? idx : e1 - 1];
            float v = (idx < e1) ? __int_as_float(q.y) : 0.f;
            unsigned b = (unsigned)q.x * 192u;
            ushort2 p = *(const ushort2*)(xall + b + po);
            ushort4 u = *(const ushort4*)(xall + b + fo);
            ap0 += v * bf2f(p.x); ap1 += v * bf2f(p.y);
            af0 += v * bf2f(u.x); an0 += v * bf2f(u.y);
            af1 += v * bf2f(u.z); an1 += v * bf2f(u.w);
        }
        ap0 += __shfl_xor(ap0, 32); ap1 += __shfl_xor(ap1, 32);
        af0 += __shfl_xor(af0, 32); af1 += __shfl_xor(af1, 32);
        an0 += __shfl_xor(an0, 32); an1 += __shfl_xor(an1, 32);
        if (h == 0) {
            int d = (int)d0;
            if (d < 62) *(float2*)(Sp + row * 248 + r * 62 + d) = make_float2(ap0, ap1);
            float* sfp = Sf + row * 148 + r * 37;
            float* snp = Sn + row * 148 + r * 37;
            if (d < 37) { sfp[d] = af0; snp[d] = an0; }
            if (d < 36) { sfp[d + 1] = af1; snp[d + 1] = an1; }
        }
    }
}

// ---------------- GEMM1 ----------------
__launch_bounds__(256)
__global__ void gemm1_kernel(const float* __restrict__ x, const float* __restrict__ S,
                             const float* __restrict__ Ws, const float* __restrict__ bs,
                             const float* __restrict__ Wr, const float* __restrict__ br,
                             float* __restrict__ h, int din) {
    __shared__ float sA[64 * 63];
    __shared__ float sW[62 * 132];
    int t = threadIdx.x;
    int i0 = blockIdx.x * 64;
    int rg = t >> 5, cg = t & 31;
    float acc[8][4] = {};
    for (int s = 0; s < 5; s++) {
        const float* Aptr; int astride;
        if (s == 0) { Aptr = x; astride = din; }
        else        { Aptr = S + (s - 1) * din; astride = 4 * din; }
        const float* Wp = (s == 0) ? Ws : (Wr + (s - 1) * H_DIM * din);
        __syncthreads();
        for (int idx = t; idx < 64 * din; idx += 256) {
            int rr = idx / din, k = idx - rr * din;
            int grow = i0 + rr;
            sA[rr * 63 + k] = (grow < N_NODES) ? Aptr[grow * astride + k] : 0.f;
        }
        for (int idx = t; idx < H_DIM * din; idx += 256) {
            int j = idx / din, k = idx - j * din;
            sW[k * 132 + j] = Wp[j * din + k];
        }
        __syncthreads();
        for (int k = 0; k < din; k++) {
            float a[8];
            #pragma unroll
            for (int rr = 0; rr < 8; rr++) a[rr] = sA[(rg * 8 + rr) * 63 + k];
            float4 w = *(const float4*)&sW[k * 132 + cg * 4];
            #pragma unroll
            for (int rr = 0; rr < 8; rr++) {
                acc[rr][0] += a[rr] * w.x; acc[rr][1] += a[rr] * w.y;
                acc[rr][2] += a[rr] * w.z; acc[rr][3] += a[rr] * w.w;
            }
        }
    }
    int j0 = cg * 4;
    float btot[4];
    #pragma unroll
    for (int cc = 0; cc < 4; cc++) {
        float b = bs[j0 + cc];
        #pragma unroll
        for (int r = 0; r < R_REL; r++) b += br[r * H_DIM + j0 + cc];
        btot[cc] = b;
    }
    #pragma unroll
    for (int rr = 0; rr < 8; rr++) {
        int grow = i0 + rg * 8 + rr;
        if (grow < N_NODES) {
            float4 o;
            o.x = fmaxf((acc[rr][0] + btot[0]) * 0.2f, 0.f);
            o.y = fmaxf((acc[rr][1] + btot[1]) * 0.2f, 0.f);
            o.z = fmaxf((acc[rr][2] + btot[2]) * 0.2f, 0.f);
            o.w = fmaxf((acc[rr][3] + btot[3]) * 0.2f, 0.f);
            *(float4*)&h[grow * H_DIM + j0] = o;
        }
    }
}

// -------- GEMM2: Yself fp32 (ct=0), Yall bf16 view-interleaved (ct=1..4) ----
__launch_bounds__(256)
__global__ void gemm2_kernel(const float* __restrict__ h, const float* __restrict__ Ws2,
                             const float* __restrict__ Wr2, float* __restrict__ Yself,
                             ushort* __restrict__ Yall, int view) {
    __shared__ float sA[128 * 65];
    __shared__ float sW[64 * 68];
    int t = threadIdx.x;
    int i0 = blockIdx.x * 128;
    int ct = blockIdx.y;
    int rg = t >> 4, cg = t & 15;
    const float* Wp = (ct == 0) ? Ws2 : (Wr2 + (ct - 1) * 64 * H_DIM);
    float acc[8][4] = {};
    for (int kc = 0; kc < 2; kc++) {
        __syncthreads();
        for (int idx = t; idx < 128 * 64; idx += 256) {
            int rr = idx >> 6, k = idx & 63;
            int grow = i0 + rr;
            sA[rr * 65 + k] = (grow < N_NODES) ? h[grow * H_DIM + kc * 64 + k] : 0.f;
        }
        for (int idx = t; idx < 64 * 64; idx += 256) {
            int j = idx >> 6, k = idx & 63;
            sW[k * 68 + j] = Wp[j * H_DIM + kc * 64 + k];
        }
        __syncthreads();
        for (int k = 0; k < 64; k++) {
            float a[8];
            #pragma unroll
            for (int rr = 0; rr < 8; rr++) a[rr] = sA[(rg * 8 + rr) * 65 + k];
            float4 w = *(const float4*)&sW[k * 68 + cg * 4];
            #pragma unroll
            for (int rr = 0; rr < 8; rr++) {
                acc[rr][0] += a[rr] * w.x; acc[rr][1] += a[rr] * w.y;
                acc[rr][2] += a[rr] * w.z; acc[rr][3] += a[rr] * w.w;
            }
        }
    }
    #pragma unroll
    for (int rr = 0; rr < 8; rr++) {
        int grow = i0 + rg * 8 + rr;
        if (grow < N_NODES) {
            if (ct == 0) {
                float4 o = make_float4(acc[rr][0], acc[rr][1], acc[rr][2], acc[rr][3]);
                *(float4*)&Yself[(size_t)grow * 64 + cg * 4] = o;
            } else {
                ushort4 o;
                o.x = f2bf(acc[rr][0]); o.y = f2bf(acc[rr][1]);
                o.z = f2bf(acc[rr][2]); o.w = f2bf(acc[rr][3]);
                // [node][r][view][64] -> node*768 + r*192 + view*64 + dim
                *(ushort4*)&Yall[(size_t)grow * 768 + (ct - 1) * 192 + view * 64 + cg * 4] = o;
            }
        }
    }
}

// ---- fold bs + sum_r br per view into one 192-float table ----
__global__ void bias_prep_kernel(const float* __restrict__ pbs, const float* __restrict__ pbr,
                                 const float* __restrict__ fbs, const float* __restrict__ fbr,
                                 const float* __restrict__ nbs, const float* __restrict__ nbr,
                                 float* __restrict__ bias3) {
    int t = threadIdx.x;
    if (t >= 192) return;
    int view = t >> 6, d = t & 63;
    const float* bs = (view == 0) ? pbs : (view == 1) ? fbs : nbs;
    const float* br = (view == 0) ? pbr : (view == 1) ? fbr : nbr;
    float b = bs[d];
    #pragma unroll
    for (int r = 0; r < R_REL; r++) b += br[r * 64 + d];
    bias3[t] = b;
}

// ---- spmm2 (all 3 views from ONE merged table) + bias + /5 + gated fusion.
__launch_bounds__(256)
__global__ void spmm2z_all_kernel(const float* __restrict__ Ysp,
                                  const float* __restrict__ Ysf,
                                  const float* __restrict__ Ysn,
                                  const ushort* __restrict__ Yall,
                                  const int* __restrict__ rp, const int2* __restrict__ cse,
                                  const float* __restrict__ bias3,
                                  const float* __restrict__ gW, const float* __restrict__ gb,
                                  float* __restrict__ z) {
    int wave = threadIdx.x >> 6, lane = threadIdx.x & 63;
    int row = blockIdx.x * 4 + wave;
    if (row >= N_NODES) return;
    int h = lane >> 5, j = lane & 31;
    unsigned d0 = 2u * (unsigned)j;
    float aP0 = 0.f, aP1 = 0.f, aF0 = 0.f, aF1 = 0.f, aN0 = 0.f, aN1 = 0.f;
    for (int r = 0; r < R_REL; r++) {
        int e0 = rp[r * N_NODES + row], e1 = rp[r * N_NODES + row + 1];
        unsigned ofs = (unsigned)(r * 192) + d0;
        int e = e0;
        for (; e + 8 <= e1; e += 8) {
            int2 qA = cse[e + h],     qB = cse[e + 2 + h];
            int2 qC = cse[e + 4 + h], qD = cse[e + 6 + h];
            unsigned oA = (unsigned)qA.x * 768u + ofs;
            unsigned oB = (unsigned)qB.x * 768u + ofs;
            unsigned oC = (unsigned)qC.x * 768u + ofs;
            unsigned oD = (unsigned)qD.x * 768u + ofs;
            ushort2 pA = *(const ushort2*)(Yall + oA);
            ushort2 fA = *(const ushort2*)(Yall + oA + 64);
            ushort2 nA = *(const ushort2*)(Yall + oA + 128);
            ushort2 pB = *(const ushort2*)(Yall + oB);
            ushort2 fB = *(const ushort2*)(Yall + oB + 64);
            ushort2 nB = *(const ushort2*)(Yall + oB + 128);
            ushort2 pC = *(const ushort2*)(Yall + oC);
            ushort2 fC = *(const ushort2*)(Yall + oC + 64);
            ushort2 nC = *(const ushort2*)(Yall + oC + 128);
            ushort2 pD = *(const ushort2*)(Yall + oD);
            ushort2 fD = *(const ushort2*)(Yall + oD + 64);
            ushort2 nD = *(const ushort2*)(Yall + oD + 128);
            float vA = __int_as_float(qA.y), vB = __int_as_float(qB.y);
            float vC = __int_as_float(qC.y), vD = __int_as_float(qD.y);
            aP0 += vA * bf2f(pA.x) + vB * bf2f(pB.x) + vC * bf2f(pC.x) + vD * bf2f(pD.x);
            aP1 += vA * bf2f(pA.y) + vB * bf2f(pB.y) + vC * bf2f(pC.y) + vD * bf2f(pD.y);
            aF0 += vA * bf2f(fA.x) + vB * bf2f(fB.x) + vC * bf2f(fC.x) + vD * bf2f(fD.x);
            aF1 += vA * bf2f(fA.y) + vB * bf2f(fB.y) + vC * bf2f(fC.y) + vD * bf2f(fD.y);
            aN0 += vA * bf2f(nA.x) + vB * bf2f(nB.x) + vC * bf2f(nC.x) + vD * bf2f(nD.x);
            aN1 += vA * bf2f(nA.y) + vB * bf2f(nB.y) + vC * bf2f(nC.y) + vD * bf2f(nD.y);
        }
        for (; e < e1; e += 2) {          // masked pair tail
            int idx = e + h;
            int2 q = cse[idx < e1 ? idx : e1 - 1];
            float v = (idx < e1) ? __int_as_float(q.y) : 0.f;
            unsigned o = (unsigned)q.x * 768u + ofs;
            ushort2 p = *(const ushort2*)(Yall + o);
            ushort2 f = *(const ushort2*)(Yall + o + 64);
            ushort2 n = *(const ushort2*)(Yall + o + 128);
            aP0 += v * bf2f(p.x); aP1 += v * bf2f(p.y);
            aF0 += v * bf2f(f.x); aF1 += v * bf2f(f.y);
            aN0 += v * bf2f(n.x); aN1 += v * bf2f(n.y);
        }
    }
    // merge the two edge-halves
    aP0 += __shfl_xor(aP0, 32); aP1 += __shfl_xor(aP1, 32);
    aF0 += __shfl_xor(aF0, 32); aF1 += __shfl_xor(aF1, 32);
    aN0 += __shfl_xor(aN0, 32); aN1 += __shfl_xor(aN1, 32);
    size_t rb = (size_t)row * 64 + d0;
    float2 ysp = *(const float2*)(Ysp + rb);
    float2 ysf = *(const float2*)(Ysf + rb);
    float2 ysn = *(const float2*)(Ysn + rb);
    aP0 = (aP0 + ysp.x + bias3[d0]) * 0.2f;
    aP1 = (aP1 + ysp.y + bias3[d0 + 1]) * 0.2f;
    aF0 = (aF0 + ysf.x + bias3[64 + d0]) * 0.2f;
    aF1 = (aF1 + ysf.y + bias3[64 + d0 + 1]) * 0.2f;
    aN0 = (aN0 + ysn.x + bias3[128 + d0]) * 0.2f;
    aN1 = (aN1 + ysn.y + bias3[128 + d0 + 1]) * 0.2f;
    float sp = aP0 * gW[d0] + aP1 * gW[d0 + 1];
    float sf = aF0 * gW[64 + d0] + aF1 * gW[64 + d0 + 1];
    float sn = aN0 * gW[128 + d0] + aN1 * gW[128 + d0 + 1];
    #pragma unroll
    for (int d = 16; d >= 1; d >>= 1) {
        sp += __shfl_xor(sp, d);
        sf += __shfl_xor(sf, d);
        sn += __shfl_xor(sn, d);
    }
    sp += gb[0]; sf += gb[1]; sn += gb[2];
    float m = fmaxf(sp, fmaxf(sf, sn));
    float ep = __expf(sp - m), ef = __expf(sf - m), en = __expf(sn - m);
    float inv = 1.f / (ep + ef + en);
    if (h == 0) {
        float2 zo;
        zo.x = (ep * aP0 + ef * aF0 + en * aN0) * inv;
        zo.y = (ep * aP1 + ef * aF1 + en * aN1) * inv;
        *(float2*)(z + rb) = zo;
    }
}

// ---- UV precompute into fused uvz record [node][U(64)|z(64)|V(64)].
// ---- U = z @ W1a^T + b1 (ct=0, also copies z into the middle); V = z @ W1b^T (ct=1).
__launch_bounds__(256)
__global__ void uvgemm_kernel(const float* __restrict__ z, const float* __restrict__ w1,
                              const float* __restrict__ b1, float* __restrict__ uvz) {
    __shared__ float sA[128 * 65];
    __shared__ float sW[64 * 68];
    int t = threadIdx.x;
    int i0 = blockIdx.x * 128;
    int ct = blockIdx.y;                  // 0 = U (+z copy), 1 = V
    int rg = t >> 4, cg = t & 15;
    for (int idx = t; idx < 128 * 64; idx += 256) {
        int rr = idx >> 6, k = idx & 63;
        int grow = i0 + rr;
        sA[rr * 65 + k] = (grow < N_NODES) ? z[(size_t)grow * 64 + k] : 0.f;
    }
    for (int idx = t; idx < 64 * 64; idx += 256) {
        int j = idx >> 6, k = idx & 63;
        sW[k * 68 + j] = w1[j * 256 + ct * 64 + k];
    }
    __syncthreads();
    float acc[8][4] = {};
    for (int k = 0; k < 64; k++) {
        float a[8];
        #pragma unroll
        for (int rr = 0; rr < 8; rr++) a[rr] = sA[(rg * 8 + rr) * 65 + k];
        float4 w = *(const float4*)&sW[k * 68 + cg * 4];
        #pragma unroll
        for (int rr = 0; rr < 8; rr++) {
            acc[rr][0] += a[rr] * w.x; acc[rr][1] += a[rr] * w.y;
            acc[rr][2] += a[rr] * w.z; acc[rr][3] += a[rr] * w.w;
        }
    }
    int j0 = cg * 4;
    float4 bv = make_float4(0.f, 0.f, 0.f, 0.f);
    if (ct == 0) {                        // fold b1 into U
        bv.x = b1[j0]; bv.y = b1[j0 + 1]; bv.z = b1[j0 + 2]; bv.w = b1[j0 + 3];
    }
    unsigned voff = (ct == 0) ? 0u : 128u;
    #pragma unroll
    for (int rr = 0; rr < 8; rr++) {
        int grow = i0 + rg * 8 + rr;
        if (grow < N_NODES) {
            float4 o = make_float4(acc[rr][0] + bv.x, acc[rr][1] + bv.y,
                                   acc[rr][2] + bv.z, acc[rr][3] + bv.w);
            *(float4*)&uvz[(size_t)grow * 192 + voff + j0] = o;
        }
    }
    if (ct == 0) {                        // copy z (already staged in sA) into middle
        for (int idx = t; idx < 128 * 64; idx += 256) {
            int rr = idx >> 6, k = idx & 63;
            int grow = i0 + rr;
            if (grow < N_NODES) uvz[(size_t)grow * 192 + 64 + k] = sA[rr * 65 + k];
        }
    }
}

// -------- decoder v9: 1 edge/thread, no j-split, fused uvz records.
// -------- Per edge: TWO contiguous 512B gather spans ([U|zs] @ s*192,
// -------- [zd|V] @ d*192+64) instead of 4 streams. hid[64] in regs,
// -------- W1c|W1d (32 KB) in LDS, direct logit write (no partials).
__launch_bounds__(256)
__global__ void decoder9_kernel(const float* __restrict__ uvz, const int* __restrict__ esrc,
                                const int* __restrict__ edst, const float* __restrict__ w1,
                                const float* __restrict__ w2, const float* __restrict__ b2,
                                float* __restrict__ out) {
    __shared__ float sW1[8192];           // 32 KB: 64 j-rows of [wc(64)|wd(64)]
    int t = threadIdx.x;
    for (int i = t; i < 2048; i += 256) {
        int j = i >> 5, c = i & 31;       // 32 float4 per j-row
        ((float4*)sW1)[i] = *(const float4*)(w1 + j * 256 + 128 + c * 4);
    }
    __syncthreads();
    int e = blockIdx.x * 256 + t;
    if (e >= ED_EDGES) return;
    int s = esrc[e], d = edst[e];
    const float4* su = (const float4*)(uvz + (size_t)s * 192);        // [U | zs]
    const float4* dv = (const float4*)(uvz + (size_t)d * 192 + 64);   // [zd | V]
    float hid[64];
    #pragma unroll
    for (int j = 0; j < 64; j++) hid[j] = 0.f;
    #pragma unroll 1
    for (int kc = 0; kc < 16; kc++) {
        float4 a = su[16 + kc];           // zs
        float4 b = dv[kc];                // zd
        float4 p, q;
        p.x = a.x * b.x; q.x = fabsf(a.x - b.x);
        p.y = a.y * b.y; q.y = fabsf(a.y - b.y);
        p.z = a.z * b.z; q.z = fabsf(a.z - b.z);
        p.w = a.w * b.w; q.w = fabsf(a.w - b.w);
        const float* wb0 = sW1 + kc * 4;
        #pragma unroll
        for (int j = 0; j < 64; j++) {
            const float* wr = wb0 + j * 128;
            float4 wc = *(const float4*)(wr);          // W1c row (broadcast)
            float4 wd = *(const float4*)(wr + 64);     // W1d row
            hid[j] += p.x * wc.x + p.y * wc.y + p.z * wc.z + p.w * wc.w
                    + q.x * wd.x + q.y * wd.y + q.z * wd.z + q.w * wd.w;
        }
    }
    float lg = b2[0];
    #pragma unroll
    for (int jj = 0; jj < 16; jj++) {
        float4 u = su[jj];                // U[s][4j..]
        float4 v = dv[16 + jj];           // V[d][4j..]
        int gj = jj * 4;
        float w0 = w2[gj], w1v = w2[gj + 1], w2v = w2[gj + 2], w3v = w2[gj + 3];
        lg += fmaxf(hid[gj]     + u.x + v.x, 0.f) * w0
            + fmaxf(hid[gj + 1] + u.y + v.y, 0.f) * w1v
            + fmaxf(hid[gj + 2] + u.z + v.z, 0.f) * w2v
            + fmaxf(hid[gj + 3] + u.w + v.w, 0.f) * w3v;
    }
    out[e] = lg;
}

// ---------------- host ----------------
extern "C" void kernel_launch(void* const* d_in, const int* in_sizes, int n_in,
                              void* d_out, int out_size, void* d_ws, size_t ws_size,
                              hipStream_t stream) {
    const float* x_p = (const float*)d_in[0];
    const float* x_f = (const float*)d_in[1];
    const float* x_n = (const float*)d_in[2];
    const float* p1_Ws = (const float*)d_in[3];  const float* p1_bs = (const float*)d_in[4];
    const float* p1_Wr = (const float*)d_in[5];  const float* p1_br = (const float*)d_in[6];
    const float* p2_Ws = (const float*)d_in[7];  const float* p2_bs = (const float*)d_in[8];
    const float* p2_Wr = (const float*)d_in[9];  const float* p2_br = (const float*)d_in[10];
    const float* f1_Ws = (const float*)d_in[11]; const float* f1_bs = (const float*)d_in[12];
    const float* f1_Wr = (const float*)d_in[13]; const float* f1_br = (const float*)d_in[14];
    const float* f2_Ws = (const float*)d_in[15]; const float* f2_bs = (const float*)d_in[16];
    const float* f2_Wr = (const float*)d_in[17]; const float* f2_br = (const float*)d_in[18];
    const float* n1_Ws = (const float*)d_in[19]; const float* n1_bs = (const float*)d_in[20];
    const float* n1_Wr = (const float*)d_in[21]; const float* n1_br = (const float*)d_in[22];
    const float* n2_Ws = (const float*)d_in[23]; const float* n2_bs = (const float*)d_in[24];
    const float* n2_Wr = (const float*)d_in[25]; const float* n2_br = (const float*)d_in[26];
    const float* gate_W = (const float*)d_in[27]; const float* gate_b = (const float*)d_in[28];
    const float* dec_W1 = (const float*)d_in[29]; const float* dec_b1 = (const float*)d_in[30];
    const float* dec_W2 = (const float*)d_in[31]; const float* dec_b2 = (const float*)d_in[32];
    const int*   adj_rows = (const int*)d_in[33];
    const int*   adj_cols = (const int*)d_in[34];
    const float* adj_vals = (const float*)d_in[35];
    const int*   edge_src = (const int*)d_in[36];
    const int*   edge_dst = (const int*)d_in[37];

    char* ws = (char*)d_ws;
    int*    rp   = (int*)(ws + WS_RP);
    int*    H    = (int*)(ws + WS_HIST);
    int*    bsum = (int*)(ws + WS_BSUM);
    float*  bias3 = (float*)(ws + WS_BIAS3);
    int2*   cse  = (int2*)(ws + WS_CV);
    int2*   tmp  = (int2*)(ws + WS_TMP);
    ushort* xall = (ushort*)(ws + WS_XALL);
    ushort* Yall = (ushort*)(ws + WS_YALL);
    float*  S_p = (float*)(ws + WS_SP);
    float*  S_f = (float*)(ws + WS_SF);
    float*  S_n = (float*)(ws + WS_SN);
    float*  h_p = (float*)(ws + WS_HPR);
    float*  h_f = (float*)(ws + WS_HF);
    float*  h_n = (float*)(ws + WS_HN);
    float*  Ys_p = (float*)(ws + WS_YSP);
    float*  Ys_f = (float*)(ws + WS_YSF);
    float*  Ys_n = (float*)(ws + WS_YSN);
    float*  z    = (float*)(ws + WS_Z);
    float*  uvz  = (float*)(ws + WS_UVZ);
    float*  out  = (float*)d_out;

    // bf16 staging of node features (merged, 384B-stride, zero-padded)
    cast_xall_kernel<<<(N_NODES * 24 + 255) / 256, 256, 0, stream>>>(x_p, x_f, x_n, xall);

    // radix CSR build: hist -> scan -> block-private scatter -> per-bucket sort
    radix_hist_kernel<<<NB, 256, 0, stream>>>(adj_rows, H);
    scan_part_kernel<<<SCB, 256, 0, stream>>>(H, bsum);
    scan_bsum_kernel<<<1, 512, 0, stream>>>(bsum, rp);
    scan_final_kernel<<<SCB, 256, 0, stream>>>(H, bsum);
    radix_scatter_kernel<<<NB, 256, 0, stream>>>(adj_rows, adj_cols, adj_vals, H, tmp);
    bucket_sort_kernel<<<KBK, 256, 0, stream>>>(tmp, H, rp, cse);

    // layer-1 spmm for all 3 views
    spmm1_all_kernel<<<N_NODES / 4, 256, 0, stream>>>(xall, rp, cse, S_p, S_f, S_n);

    // layer-1 GEMMs -> h_v (fp32)
    int g1 = (N_NODES + 63) / 64;
    gemm1_kernel<<<g1, 256, 0, stream>>>(x_p, S_p, p1_Ws, p1_bs, p1_Wr, p1_br, h_p, 62);
    gemm1_kernel<<<g1, 256, 0, stream>>>(x_f, S_f, f1_Ws, f1_bs, f1_Wr, f1_br, h_f, 37);
    gemm1_kernel<<<g1, 256, 0, stream>>>(x_n, S_n, n1_Ws, n1_bs, n1_Wr, n1_br, h_n, 37);

    // layer-2 GEMMs: Yself fp32 + merged view-interleaved Yall bf16
    dim3 g2((N_NODES + 127) / 128, 5);
    gemm2_kernel<<<g2, 256, 0, stream>>>(h_p, p2_Ws, p2_Wr, Ys_p, Yall, 0);
    gemm2_kernel<<<g2, 256, 0, stream>>>(h_f, f2_Ws, f2_Wr, Ys_f, Yall, 1);
    gemm2_kernel<<<g2, 256, 0, stream>>>(h_n, n2_Ws, n2_Wr, Ys_n, Yall, 2);

    // fold biases, then spmm2 (all views, one table) + gated fusion -> z
    bias_prep_kernel<<<1, 192, 0, stream>>>(p2_bs, p2_br, f2_bs, f2_br, n2_bs, n2_br, bias3);
    spmm2z_all_kernel<<<N_NODES / 4, 256, 0, stream>>>(
        Ys_p, Ys_f, Ys_n, Yall, rp, cse, bias3, gate_W, gate_b, z);

    // fused per-node record [U | z | V] (Yall is dead now)
    dim3 guv((N_NODES + 127) / 128, 2);
    uvgemm_kernel<<<guv, 256, 0, stream>>>(z, dec_W1, dec_b1, uvz);

    // edge decoder: 1 edge/thread, 2 gather spans, direct logits
    decoder9_kernel<<<(ED_EDGES + 255) / 256, 256, 0, stream>>>(
        uvz, edge_src, edge_dst, dec_W1, dec_W2, dec_b2, out);
}